// Round 1
// baseline (510.336 us; speedup 1.0000x reference)
//
#include <hip/hip_runtime.h>

using f32x4  = __attribute__((ext_vector_type(4))) float;
using bf16x8 = __attribute__((ext_vector_type(8))) __bf16;

#define AS1(p) ((__attribute__((address_space(1))) void*)(p))
#define AS3(p) ((__attribute__((address_space(3))) void*)(p))

__device__ __forceinline__ unsigned short f2bf(float f) {
    unsigned u = __float_as_uint(f);
    unsigned r = u + 0x7FFFu + ((u >> 16) & 1u);
    return (unsigned short)(r >> 16);
}

__device__ __forceinline__ f32x4 mfma16(bf16x8 a, bf16x8 b, f32x4 c) {
    return __builtin_amdgcn_mfma_f32_16x16x32_bf16(a, b, c, 0, 0, 0);
}

// ---------------- prep kernels ----------------

__global__ void k_cvt_hidden(const float* __restrict__ in, unsigned short* __restrict__ out, long n) {
    long i0 = ((long)blockIdx.x * 256 + threadIdx.x) * 8;
    long stride = (long)gridDim.x * 256 * 8;
    for (long i = i0; i < n; i += stride) {
        float4 a = *(const float4*)&in[i];
        float4 b = *(const float4*)&in[i + 4];
        uint4 v;
        v.x = f2bf(a.x) | ((unsigned)f2bf(a.y) << 16);
        v.y = f2bf(a.z) | ((unsigned)f2bf(a.w) << 16);
        v.z = f2bf(b.x) | ((unsigned)f2bf(b.y) << 16);
        v.w = f2bf(b.z) | ((unsigned)f2bf(b.w) << 16);
        *(uint4*)&out[i] = v;
    }
}

// out[2][1280][1280] bf16; rows m<1232 copied flat from src (layout [16*77][1280]), rest zero
__global__ void k_prep_enc(const float* __restrict__ enc, const float* __restrict__ qual,
                           unsigned short* __restrict__ out) {
    long total = 2L * 1280 * 1280 / 4;
    long i0 = (long)blockIdx.x * 256 + threadIdx.x;
    long stride = (long)gridDim.x * 256;
    for (long i = i0; i < total; i += stride) {
        long e = i * 4;
        int g = (int)(e / (1280L * 1280));
        long rem = e - (long)g * 1280 * 1280;
        int m = (int)(rem / 1280);
        uint2 v = {0u, 0u};
        if (m < 1232) {
            const float* src = (g ? qual : enc) + rem;
            float4 a = *(const float4*)src;
            v.x = f2bf(a.x) | ((unsigned)f2bf(a.y) << 16);
            v.y = f2bf(a.z) | ((unsigned)f2bf(a.w) << 16);
        }
        *(uint2*)&out[e] = v;
    }
}

// Transposed bf16 weights (B^T layout [N][K]); SCALE folded into Wq
__global__ void k_prep_w(const float* __restrict__ Wq, const float* __restrict__ Wout,
                         const float* __restrict__ Wks, const float* __restrict__ Wvs,
                         const float* __restrict__ Wkq, const float* __restrict__ Wvq,
                         unsigned short* __restrict__ wq_bt, unsigned short* __restrict__ wout_bt,
                         unsigned short* __restrict__ wkv_bt /* [2][1280*1280] */) {
    const float scale = 0.11180339887498949f; // 80^-0.5
    long i0 = (long)blockIdx.x * 256 + threadIdx.x;
    long stride = (long)gridDim.x * 256;
    for (long i = i0; i < 4096000L; i += stride) {
        if (i < 409600) {
            int n = (int)(i / 640), k = (int)(i % 640);
            wq_bt[i] = f2bf(Wq[(size_t)k * 640 + n] * scale);
        } else if (i < 819200) {
            long j = i - 409600;
            int n = (int)(j / 640), k = (int)(j % 640);
            wout_bt[j] = f2bf(Wout[(size_t)k * 640 + n]);
        } else {
            long j = i - 819200;
            int g = (int)(j / (1280L * 1280));
            long r = j - (long)g * 1280 * 1280;
            int n = (int)(r / 1280), k = (int)(r % 1280);
            const float* Wk = g ? Wkq : Wks;
            const float* Wv = g ? Wvq : Wvs;
            float val = (n < 640) ? Wk[(size_t)k * 640 + n] : Wv[(size_t)k * 640 + (n - 640)];
            wkv_bt[j] = f2bf(val);
        }
    }
}

// kv: [2][1280][1280] raw GEMM out (cols 0..640 = K, 640..1280 = V)
// K -> [2][16][8][77][80], V -> transposed [2][16][8][80][77]
__global__ void k_scatter(const unsigned short* __restrict__ kv,
                          unsigned short* __restrict__ Kgm, unsigned short* __restrict__ Vtgm) {
    const long per = 1232L * 1280;
    long i0 = (long)blockIdx.x * 256 + threadIdx.x;
    long stride = (long)gridDim.x * 256;
    for (long i = i0; i < 2 * per; i += stride) {
        int g = (int)(i / per);
        long r = i - (long)g * per;
        int m = (int)(r / 1280), j = (int)(r % 1280);
        int b = m / 77, l = m % 77;
        unsigned short val = kv[(size_t)g * 1280 * 1280 + (size_t)m * 1280 + j];
        if (j < 640) {
            int h = j / 80, d = j % 80;
            Kgm[(((size_t)g * 16 + b) * 8 + h) * 6160 + l * 80 + d] = val;
        } else {
            int j2 = j - 640, h = j2 / 80, d = j2 % 80;
            Vtgm[(((size_t)g * 16 + b) * 8 + h) * 6160 + d * 77 + l] = val;
        }
    }
}

// ---------------- GEMM: C[M][N] = A[M][K] * Bt[N][K]^T  (m97-style 128x128) ----------------

template <int OUT_F32>
__global__ __launch_bounds__(256) void gemm_bt(
    const unsigned short* __restrict__ A, const unsigned short* __restrict__ Bt,
    void* __restrict__ Cv, int K, int N, long zA, long zB, long zC)
{
    const unsigned short* Ab = A + (size_t)blockIdx.z * zA;
    const unsigned short* Bb = Bt + (size_t)blockIdx.z * zB;
    __shared__ __attribute__((aligned(16))) unsigned short As[128 * 32];
    __shared__ __attribute__((aligned(16))) unsigned short Bs[128 * 32];
    const int tid = threadIdx.x, lane = tid & 63, wv = tid >> 6;
    const int wm = wv >> 1, wn = wv & 1;
    const size_t m0 = (size_t)blockIdx.x * 128;
    const int n0 = blockIdx.y * 128;
    const int srow = lane >> 2;        // row within 16-row staging chunk
    const int scol = (lane & 3) * 8;   // col (8 bf16 = 16B)
    f32x4 acc[4][4] = {};
    for (int k0 = 0; k0 < K; k0 += 32) {
        for (int c = wv; c < 8; c += 4) {
            __builtin_amdgcn_global_load_lds(AS1(Ab + (m0 + c * 16 + srow) * K + k0 + scol),
                                             AS3(&As[c * 512]), 16, 0, 0);
            __builtin_amdgcn_global_load_lds(AS1(Bb + ((size_t)(n0 + c * 16 + srow)) * K + k0 + scol),
                                             AS3(&Bs[c * 512]), 16, 0, 0);
        }
        asm volatile("s_waitcnt vmcnt(0)" ::: "memory");
        __syncthreads();
        const int ko = (lane >> 4) * 8;
        bf16x8 a[4], b[4];
#pragma unroll
        for (int i = 0; i < 4; ++i) {
            a[i] = *(const bf16x8*)&As[(wm * 64 + i * 16 + (lane & 15)) * 32 + ko];
            b[i] = *(const bf16x8*)&Bs[(wn * 64 + i * 16 + (lane & 15)) * 32 + ko];
        }
#pragma unroll
        for (int mi = 0; mi < 4; ++mi)
#pragma unroll
            for (int ni = 0; ni < 4; ++ni)
                acc[mi][ni] = mfma16(a[mi], b[ni], acc[mi][ni]);
        __syncthreads();
    }
#pragma unroll
    for (int mi = 0; mi < 4; ++mi) {
#pragma unroll
        for (int ni = 0; ni < 4; ++ni) {
            size_t row = m0 + wm * 64 + mi * 16 + ((lane >> 4) * 4);
            int col = n0 + wn * 64 + ni * 16 + (lane & 15);
#pragma unroll
            for (int i = 0; i < 4; ++i) {
                float v = acc[mi][ni][i];
                if (OUT_F32)
                    ((float*)Cv + (size_t)blockIdx.z * zC)[(row + i) * N + col] = v;
                else
                    ((unsigned short*)Cv + (size_t)blockIdx.z * zC)[(row + i) * N + col] = f2bf(v);
            }
        }
    }
}

// ---------------- fused dual attention ----------------
// grid (32 s-tiles, 8 h, 16 b), 512 threads (8 waves), 128 query rows/block
__global__ __launch_bounds__(512) void attn_kernel(
    const unsigned short* __restrict__ Q,    // [16][4096][640] bf16 (pre-scaled)
    const unsigned short* __restrict__ Kg,   // [2][16][8][77][80]
    const unsigned short* __restrict__ Vtg,  // [2][16][8][80][77]
    const float* __restrict__ fw,            // [2]
    unsigned short* __restrict__ fused)      // [16][4096][640] bf16
{
    const int b = blockIdx.z, h = blockIdx.y;
    const int s0 = blockIdx.x * 128;
    __shared__ __attribute__((aligned(16))) unsigned short Qs[128 * 104];
    __shared__ __attribute__((aligned(16))) unsigned short Ks[2][80 * 104];
    __shared__ __attribute__((aligned(16))) unsigned short Vts[2][80 * 104];
    __shared__ __attribute__((aligned(16))) unsigned short Ps[128 * 104];
    const int tid = threadIdx.x, lane = tid & 63, wv = tid >> 6;

    // stage Q [128][104] (cols 80..103 zero)
    for (int idx = tid; idx < 128 * 13; idx += 512) {
        int row = idx / 13, ch = idx % 13;
        uint4 v = {0u, 0u, 0u, 0u};
        if (ch < 10)
            v = *(const uint4*)(Q + (size_t)(b * 4096 + s0 + row) * 640 + h * 80 + ch * 8);
        *(uint4*)&Qs[row * 104 + ch * 8] = v;
    }
    // stage K [2][80][104] (rows 77..79 zero, cols 80..103 zero)
    for (int idx = tid; idx < 2 * 80 * 13; idx += 512) {
        int g = idx / (80 * 13); int rem = idx - g * 80 * 13; int l = rem / 13, ch = rem % 13;
        uint4 v = {0u, 0u, 0u, 0u};
        if (l < 77 && ch < 10)
            v = *(const uint4*)(Kg + ((size_t)(g * 16 + b) * 8 + h) * 6160 + l * 80 + ch * 8);
        *(uint4*)&Ks[g][l * 104 + ch * 8] = v;
    }
    // stage V^T [2][80][104] (cols l: 77..103 zero)
    for (int idx = tid; idx < 2 * 80 * 13; idx += 512) {
        int g = idx / (80 * 13); int rem = idx - g * 80 * 13; int d = rem / 13, ch = rem % 13;
        const unsigned short* src = Vtg + ((size_t)(g * 16 + b) * 8 + h) * 6160 + d * 77;
        unsigned t[8];
#pragma unroll
        for (int j = 0; j < 8; ++j) { int l = ch * 8 + j; t[j] = (l < 77) ? (unsigned)src[l] : 0u; }
        uint4 v;
        v.x = t[0] | (t[1] << 16); v.y = t[2] | (t[3] << 16);
        v.z = t[4] | (t[5] << 16); v.w = t[6] | (t[7] << 16);
        *(uint4*)&Vts[g][d * 104 + ch * 8] = v;
    }
    __syncthreads();

    float f0 = fw[0], f1 = fw[1];
    float fm = fmaxf(f0, f1);
    float e0 = __expf(f0 - fm), e1 = __expf(f1 - fm);
    float w01[2]; w01[0] = e0 / (e0 + e1); w01[1] = e1 / (e0 + e1);

    const int l15 = lane & 15;
    const int ko = (lane >> 4) * 8;
    const int arow = wv * 16 + l15;   // A-frag row for this wave (Q / P)

    f32x4 o[2][5] = {};

    bf16x8 aq[3];
#pragma unroll
    for (int kk = 0; kk < 3; ++kk)
        aq[kk] = *(const bf16x8*)&Qs[arow * 104 + kk * 32 + ko];

    for (int g = 0; g < 2; ++g) {
        // scores = Q * K^T  (rows: this wave's 16, cols: 80 padded)
        f32x4 s[5] = {};
#pragma unroll
        for (int t = 0; t < 5; ++t)
#pragma unroll
            for (int kk = 0; kk < 3; ++kk) {
                bf16x8 bk = *(const bf16x8*)&Ks[g][(t * 16 + l15) * 104 + kk * 32 + ko];
                s[t] = mfma16(aq[kk], bk, s[t]);
            }
        __syncthreads();
        // in-register softmax (16-lane groups hold one row's 16 cols per tile)
#pragma unroll
        for (int i = 0; i < 4; ++i) {
            float m = -1e30f;
#pragma unroll
            for (int t = 0; t < 5; ++t) { if (t * 16 + l15 < 77) m = fmaxf(m, s[t][i]); }
            m = fmaxf(m, __shfl_xor(m, 1));
            m = fmaxf(m, __shfl_xor(m, 2));
            m = fmaxf(m, __shfl_xor(m, 4));
            m = fmaxf(m, __shfl_xor(m, 8));
            float p[5]; float sum = 0.f;
#pragma unroll
            for (int t = 0; t < 5; ++t) {
                p[t] = (t * 16 + l15 < 77) ? __expf(s[t][i] - m) : 0.f;
                sum += p[t];
            }
            sum += __shfl_xor(sum, 1);
            sum += __shfl_xor(sum, 2);
            sum += __shfl_xor(sum, 4);
            sum += __shfl_xor(sum, 8);
            float rs = 1.0f / sum;
            int prow = wv * 16 + (lane >> 4) * 4 + i;
#pragma unroll
            for (int t = 0; t < 5; ++t)
                Ps[prow * 104 + t * 16 + l15] = f2bf(p[t] * rs);
            Ps[prow * 104 + 80 + l15] = 0;   // zero cols 80..95
        }
        __syncthreads();
        // O += P * V   (B^T = Vt)
#pragma unroll
        for (int kk = 0; kk < 3; ++kk) {
            bf16x8 ap = *(const bf16x8*)&Ps[arow * 104 + kk * 32 + ko];
#pragma unroll
            for (int t = 0; t < 5; ++t) {
                bf16x8 bv = *(const bf16x8*)&Vts[g][(t * 16 + l15) * 104 + kk * 32 + ko];
                o[g][t] = mfma16(ap, bv, o[g][t]);
            }
        }
    }
    // fuse + store bf16
#pragma unroll
    for (int t = 0; t < 5; ++t) {
        int d = t * 16 + l15;
#pragma unroll
        for (int i = 0; i < 4; ++i) {
            int srow = s0 + wv * 16 + (lane >> 4) * 4 + i;
            float v = w01[0] * o[0][t][i] + w01[1] * o[1][t][i];
            fused[(size_t)(b * 4096 + srow) * 640 + h * 80 + d] = f2bf(v);
        }
    }
}

// ---------------- launcher ----------------

extern "C" void kernel_launch(void* const* d_in, const int* in_sizes, int n_in,
                              void* d_out, int out_size, void* d_ws, size_t ws_size,
                              hipStream_t stream) {
    const float* hidden = (const float*)d_in[0];
    const float* enc    = (const float*)d_in[1];
    const float* qual   = (const float*)d_in[2];
    const float* Wq     = (const float*)d_in[3];
    const float* Wks    = (const float*)d_in[4];
    const float* Wvs    = (const float*)d_in[5];
    const float* Wkq    = (const float*)d_in[6];
    const float* Wvq    = (const float*)d_in[7];
    const float* Wout   = (const float*)d_in[8];
    const float* fw     = (const float*)d_in[9];
    float* out = (float*)d_out;

    char* ws = (char*)d_ws;
    unsigned short* hid_bf  = (unsigned short*)(ws + 0);          // 83,886,080 B (reused as `fused`)
    unsigned short* Qb      = (unsigned short*)(ws + 83886080);   // 83,886,080 B
    unsigned short* encp    = (unsigned short*)(ws + 167772160);  // [2][1280][1280]  6,553,600 B
    unsigned short* wq_bt   = (unsigned short*)(ws + 174325760);  // 819,200 B
    unsigned short* wout_bt = (unsigned short*)(ws + 175144960);  // 819,200 B
    unsigned short* wkv_bt  = (unsigned short*)(ws + 175964160);  // [2][1280][1280]  6,553,600 B
    unsigned short* kvout   = (unsigned short*)(ws + 182517760);  // [2][1280][1280]  6,553,600 B
    unsigned short* Kgm     = (unsigned short*)(ws + 189071360);  // 3,153,920 B
    unsigned short* Vtgm    = (unsigned short*)(ws + 192225280);  // 3,153,920 B  (total 195,379,200 B)

    k_cvt_hidden<<<dim3(2048), dim3(256), 0, stream>>>(hidden, hid_bf, 41943040L);
    k_prep_enc<<<dim3(1024), dim3(256), 0, stream>>>(enc, qual, encp);
    k_prep_w<<<dim3(1024), dim3(256), 0, stream>>>(Wq, Wout, Wks, Wvs, Wkq, Wvq, wq_bt, wout_bt, wkv_bt);
    gemm_bt<0><<<dim3(10, 10, 2), dim3(256), 0, stream>>>(encp, wkv_bt, (void*)kvout, 1280, 1280,
                                                          1280L * 1280, 1280L * 1280, 1280L * 1280);
    k_scatter<<<dim3(1024), dim3(256), 0, stream>>>(kvout, Kgm, Vtgm);
    gemm_bt<0><<<dim3(512, 5, 1), dim3(256), 0, stream>>>(hid_bf, wq_bt, (void*)Qb, 640, 640, 0L, 0L, 0L);
    attn_kernel<<<dim3(32, 8, 16), dim3(512), 0, stream>>>(Qb, Kgm, Vtgm, fw, hid_bf);
    gemm_bt<1><<<dim3(512, 5, 1), dim3(256), 0, stream>>>(hid_bf, wout_bt, (void*)out, 640, 640, 0L, 0L, 0L);
}

// Round 2
// 435.285 us; speedup vs baseline: 1.1724x; 1.1724x over previous
//
#include <hip/hip_runtime.h>

using f32x4  = __attribute__((ext_vector_type(4))) float;
using bf16x8 = __attribute__((ext_vector_type(8))) __bf16;

#define AS1(p) ((__attribute__((address_space(1))) void*)(p))
#define AS3(p) ((__attribute__((address_space(3))) void*)(p))

__device__ __forceinline__ unsigned short f2bf(float f) {
    unsigned u = __float_as_uint(f);
    unsigned r = u + 0x7FFFu + ((u >> 16) & 1u);
    return (unsigned short)(r >> 16);
}

__device__ __forceinline__ f32x4 mfma16(bf16x8 a, bf16x8 b, f32x4 c) {
    return __builtin_amdgcn_mfma_f32_16x16x32_bf16(a, b, c, 0, 0, 0);
}

// ---------------- prep kernels ----------------

__global__ void k_cvt_hidden(const float* __restrict__ in, unsigned short* __restrict__ out, long n) {
    long i0 = ((long)blockIdx.x * 256 + threadIdx.x) * 8;
    long stride = (long)gridDim.x * 256 * 8;
    for (long i = i0; i < n; i += stride) {
        float4 a = *(const float4*)&in[i];
        float4 b = *(const float4*)&in[i + 4];
        uint4 v;
        v.x = f2bf(a.x) | ((unsigned)f2bf(a.y) << 16);
        v.y = f2bf(a.z) | ((unsigned)f2bf(a.w) << 16);
        v.z = f2bf(b.x) | ((unsigned)f2bf(b.y) << 16);
        v.w = f2bf(b.z) | ((unsigned)f2bf(b.w) << 16);
        *(uint4*)&out[i] = v;
    }
}

// out[2][1280][1280] bf16; rows m<1232 copied flat from src (layout [16*77][1280]), rest zero
__global__ void k_prep_enc(const float* __restrict__ enc, const float* __restrict__ qual,
                           unsigned short* __restrict__ out) {
    long total = 2L * 1280 * 1280 / 4;
    long i0 = (long)blockIdx.x * 256 + threadIdx.x;
    long stride = (long)gridDim.x * 256;
    for (long i = i0; i < total; i += stride) {
        long e = i * 4;
        int g = (int)(e / (1280L * 1280));
        long rem = e - (long)g * 1280 * 1280;
        int m = (int)(rem / 1280);
        uint2 v = {0u, 0u};
        if (m < 1232) {
            const float* src = (g ? qual : enc) + rem;
            float4 a = *(const float4*)src;
            v.x = f2bf(a.x) | ((unsigned)f2bf(a.y) << 16);
            v.y = f2bf(a.z) | ((unsigned)f2bf(a.w) << 16);
        }
        *(uint2*)&out[e] = v;
    }
}

// Transposed bf16 weights (B^T layout [N][K]); SCALE folded into Wq
__global__ void k_prep_w(const float* __restrict__ Wq, const float* __restrict__ Wout,
                         const float* __restrict__ Wks, const float* __restrict__ Wvs,
                         const float* __restrict__ Wkq, const float* __restrict__ Wvq,
                         unsigned short* __restrict__ wq_bt, unsigned short* __restrict__ wout_bt,
                         unsigned short* __restrict__ wkv_bt /* [2][1280*1280] */) {
    const float scale = 0.11180339887498949f; // 80^-0.5
    long i0 = (long)blockIdx.x * 256 + threadIdx.x;
    long stride = (long)gridDim.x * 256;
    for (long i = i0; i < 4096000L; i += stride) {
        if (i < 409600) {
            int n = (int)(i / 640), k = (int)(i % 640);
            wq_bt[i] = f2bf(Wq[(size_t)k * 640 + n] * scale);
        } else if (i < 819200) {
            long j = i - 409600;
            int n = (int)(j / 640), k = (int)(j % 640);
            wout_bt[j] = f2bf(Wout[(size_t)k * 640 + n]);
        } else {
            long j = i - 819200;
            int g = (int)(j / (1280L * 1280));
            long r = j - (long)g * 1280 * 1280;
            int n = (int)(r / 1280), k = (int)(r % 1280);
            const float* Wk = g ? Wkq : Wks;
            const float* Wv = g ? Wvq : Wvs;
            float val = (n < 640) ? Wk[(size_t)k * 640 + n] : Wv[(size_t)k * 640 + (n - 640)];
            wkv_bt[j] = f2bf(val);
        }
    }
}

// kv: [2][1280][1280] raw GEMM out (cols 0..640 = K, 640..1280 = V)
// K -> Kg2[2][16][8][80][104]  (row l, col d; zeros for l>=77 or d>=80)
// V -> Vt2[2][16][8][80][104]  (row d, col l; zeros for l>=77)
__global__ void k_scatter(const unsigned short* __restrict__ kv,
                          unsigned short* __restrict__ Kg2, unsigned short* __restrict__ Vt2) {
    const long per = 2L * 16 * 8 * 80 * 52;  // uint elements per array
    const long total = 2 * per;
    long i0 = (long)blockIdx.x * 256 + threadIdx.x;
    long stride = (long)gridDim.x * 256;
    for (long i = i0; i < total; i += stride) {
        int arr = (int)(i / per);
        long r = i - (long)arr * per;
        int c2 = (int)(r % 52); r /= 52;
        int row = (int)(r % 80); r /= 80;
        int h = (int)(r % 8); r /= 8;
        int b = (int)(r % 16); r /= 16;
        int g = (int)r;
        size_t dst_u = (((size_t)g * 16 + b) * 8 + h) * 4160 + row * 52 + c2;
        unsigned val = 0;
        if (arr == 0) {
            // K: row=l, cols d = 2c2, 2c2+1
            int d0 = 2 * c2;
            if (row < 77 && d0 < 80)
                val = *(const unsigned*)&kv[(size_t)g * 1638400 + ((size_t)b * 77 + row) * 1280 + h * 80 + d0];
            ((unsigned*)Kg2)[dst_u] = val;
        } else {
            // V^T: row=d, cols l = 2c2, 2c2+1
            int l0 = 2 * c2;
            unsigned v0 = 0, v1 = 0;
            if (l0 < 77)
                v0 = kv[(size_t)g * 1638400 + ((size_t)b * 77 + l0) * 1280 + 640 + h * 80 + row];
            if (l0 + 1 < 77)
                v1 = kv[(size_t)g * 1638400 + ((size_t)b * 77 + l0 + 1) * 1280 + 640 + h * 80 + row];
            ((unsigned*)Vt2)[dst_u] = v0 | (v1 << 16);
        }
    }
}

// ---------------- GEMM: C[M][N] = A[M][K] * Bt[N][K]^T  (m97-style 128x128) ----------------

template <int OUT_F32>
__global__ __launch_bounds__(256) void gemm_bt(
    const unsigned short* __restrict__ A, const unsigned short* __restrict__ Bt,
    void* __restrict__ Cv, int K, int N, long zA, long zB, long zC)
{
    const unsigned short* Ab = A + (size_t)blockIdx.z * zA;
    const unsigned short* Bb = Bt + (size_t)blockIdx.z * zB;
    __shared__ __attribute__((aligned(16))) unsigned short As[128 * 32];
    __shared__ __attribute__((aligned(16))) unsigned short Bs[128 * 32];
    const int tid = threadIdx.x, lane = tid & 63, wv = tid >> 6;
    const int wm = wv >> 1, wn = wv & 1;
    const size_t m0 = (size_t)blockIdx.x * 128;
    const int n0 = blockIdx.y * 128;
    const int srow = lane >> 2;        // row within 16-row staging chunk
    const int scol = (lane & 3) * 8;   // col (8 bf16 = 16B)
    f32x4 acc[4][4] = {};
    for (int k0 = 0; k0 < K; k0 += 32) {
        for (int c = wv; c < 8; c += 4) {
            __builtin_amdgcn_global_load_lds(AS1(Ab + (m0 + c * 16 + srow) * K + k0 + scol),
                                             AS3(&As[c * 512]), 16, 0, 0);
            __builtin_amdgcn_global_load_lds(AS1(Bb + ((size_t)(n0 + c * 16 + srow)) * K + k0 + scol),
                                             AS3(&Bs[c * 512]), 16, 0, 0);
        }
        asm volatile("s_waitcnt vmcnt(0)" ::: "memory");
        __syncthreads();
        const int ko = (lane >> 4) * 8;
        bf16x8 a[4], b[4];
#pragma unroll
        for (int i = 0; i < 4; ++i) {
            a[i] = *(const bf16x8*)&As[(wm * 64 + i * 16 + (lane & 15)) * 32 + ko];
            b[i] = *(const bf16x8*)&Bs[(wn * 64 + i * 16 + (lane & 15)) * 32 + ko];
        }
#pragma unroll
        for (int mi = 0; mi < 4; ++mi)
#pragma unroll
            for (int ni = 0; ni < 4; ++ni)
                acc[mi][ni] = mfma16(a[mi], b[ni], acc[mi][ni]);
        __syncthreads();
    }
#pragma unroll
    for (int mi = 0; mi < 4; ++mi) {
#pragma unroll
        for (int ni = 0; ni < 4; ++ni) {
            size_t row = m0 + wm * 64 + mi * 16 + ((lane >> 4) * 4);
            int col = n0 + wn * 64 + ni * 16 + (lane & 15);
#pragma unroll
            for (int i = 0; i < 4; ++i) {
                float v = acc[mi][ni][i];
                if (OUT_F32)
                    ((float*)Cv + (size_t)blockIdx.z * zC)[(row + i) * N + col] = v;
                else
                    ((unsigned short*)Cv + (size_t)blockIdx.z * zC)[(row + i) * N + col] = f2bf(v);
            }
        }
    }
}

// ---------------- fused dual attention (swapped QK^T, P in registers) ----------------
// grid (32 s-tiles, 8 h, 16 b), 512 threads (8 waves), 16 query rows per wave.
// LDS: K[2][80][104] + Vt[2][80][104] = 66,560 B -> 2 blocks/CU.
__global__ __launch_bounds__(512, 4) void attn_kernel(
    const unsigned short* __restrict__ Q,    // [16][4096][640] bf16 (pre-scaled by SCALE via Wq)
    const unsigned short* __restrict__ Kg2,  // [2][16][8][80][104]
    const unsigned short* __restrict__ Vt2,  // [2][16][8][80][104]
    const float* __restrict__ fw,            // [2]
    unsigned short* __restrict__ fused)      // [16][4096][640] bf16
{
    const int b = blockIdx.z, h = blockIdx.y;
    const int s0 = blockIdx.x * 128;
    __shared__ __attribute__((aligned(16))) unsigned short lds[4 * 8320]; // Kg0,Kg1,Vg0,Vg1
    const int tid = threadIdx.x, lane = tid & 63, wv = tid >> 6;
    const int l15 = lane & 15, q = lane >> 4;

    // ---- Q fragments: straight global -> VGPR (B-operand rows = this wave's 16 queries)
    const unsigned short* qrow = Q + ((size_t)b * 4096 + s0 + wv * 16 + l15) * 640 + h * 80;
    bf16x8 aq[3];
    aq[0] = *(const bf16x8*)(qrow + q * 8);
    aq[1] = *(const bf16x8*)(qrow + 32 + q * 8);
    if (q < 2) aq[2] = *(const bf16x8*)(qrow + 64 + q * 8);
    else       aq[2] = bf16x8{};

    // ---- stage K/V (4 x 1040 chunks of 16B) via global_load_lds, LDS linear
    {
        const unsigned short* sK0 = Kg2 + ((size_t)(b * 8 + h)) * 8320;
        const unsigned short* sK1 = Kg2 + ((size_t)((16 + b) * 8 + h)) * 8320;
        const unsigned short* sV0 = Vt2 + ((size_t)(b * 8 + h)) * 8320;
        const unsigned short* sV1 = Vt2 + ((size_t)((16 + b) * 8 + h)) * 8320;
#pragma unroll
        for (int it = 0; it < 9; ++it) {
            int chunk = it * 512 + tid;
            if (chunk < 4160) {
                int c = chunk;
                const unsigned short* src = sK0 + (size_t)c * 8;
                if (c >= 1040) src = sK1 + (size_t)(c - 1040) * 8;
                if (c >= 2080) src = sV0 + (size_t)(c - 2080) * 8;
                if (c >= 3120) src = sV1 + (size_t)(c - 3120) * 8;
                __builtin_amdgcn_global_load_lds(AS1(src), AS3(&lds[(size_t)(it * 512 + wv * 64) * 8]),
                                                 16, 0, 0);
            }
        }
    }
    asm volatile("s_waitcnt vmcnt(0)" ::: "memory");
    __syncthreads();

    float f0 = fw[0], f1 = fw[1];
    float fm = fmaxf(f0, f1);
    float e0 = __expf(f0 - fm), e1 = __expf(f1 - fm);
    float w0 = e0 / (e0 + e1), w1 = e1 / (e0 + e1);

    f32x4 o0[5] = {}, o1[5] = {};

#pragma unroll
    for (int g = 0; g < 2; ++g) {
        const unsigned short* Ks = &lds[g * 8320];
        const unsigned short* Vs = &lds[(2 + g) * 8320];

        // ---- S^T = K * Q^T : lane holds col s=l15, rows l = 16t + 4q + i
        f32x4 s[5] = {};
#pragma unroll
        for (int t = 0; t < 5; ++t)
#pragma unroll
            for (int kk = 0; kk < 3; ++kk) {
                bf16x8 ak = *(const bf16x8*)&Ks[(t * 16 + l15) * 104 + kk * 32 + q * 8];
                s[t] = mfma16(ak, aq[kk], s[t]);
            }

        // ---- softmax over l (77 valid) for this lane's query column
        float mx = -3.0e38f;
#pragma unroll
        for (int t = 0; t < 4; ++t)
#pragma unroll
            for (int i = 0; i < 4; ++i) mx = fmaxf(mx, s[t][i]);
#pragma unroll
        for (int i = 0; i < 4; ++i)
            if (q * 4 + i < 13) mx = fmaxf(mx, s[4][i]);
        mx = fmaxf(mx, __shfl_xor(mx, 16));
        mx = fmaxf(mx, __shfl_xor(mx, 32));
        float p[5][4];
        float sum = 0.f;
#pragma unroll
        for (int t = 0; t < 4; ++t)
#pragma unroll
            for (int i = 0; i < 4; ++i) { p[t][i] = __expf(s[t][i] - mx); sum += p[t][i]; }
#pragma unroll
        for (int i = 0; i < 4; ++i) {
            p[4][i] = (q * 4 + i < 13) ? __expf(s[4][i] - mx) : 0.f;
            sum += p[4][i];
        }
        sum += __shfl_xor(sum, 16);
        sum += __shfl_xor(sum, 32);
        float rs = 1.0f / sum;

        // ---- pack P quads (bf16) : myq[t] = this lane's 4 values (l = 16t+4q..+3)
        uint2 myq[5];
#pragma unroll
        for (int t = 0; t < 5; ++t) {
            myq[t].x = (unsigned)f2bf(p[t][0] * rs) | ((unsigned)f2bf(p[t][1] * rs) << 16);
            myq[t].y = (unsigned)f2bf(p[t][2] * rs) | ((unsigned)f2bf(p[t][3] * rs) << 16);
        }
        // ---- butterfly step 1 (xor16): assemble quad-pairs per tile
        uint4 A[6];
#pragma unroll
        for (int t = 0; t < 5; ++t) {
            unsigned px = __shfl_xor((int)myq[t].x, 16);
            unsigned py = __shfl_xor((int)myq[t].y, 16);
            if (q & 1) A[t] = uint4{px, py, myq[t].x, myq[t].y};
            else       A[t] = uint4{myq[t].x, myq[t].y, px, py};
        }
        A[5] = uint4{0u, 0u, 0u, 0u};

        // ---- PV: per k-slice, butterfly step 2 (xor32) delivers the A-fragment
        f32x4* o = g ? o1 : o0;
#pragma unroll
        for (int kk = 0; kk < 3; ++kk) {
            uint4 own = (q >> 1) ? A[2 * kk + 1] : A[2 * kk];
            uint4 snd = (q >> 1) ? A[2 * kk] : A[2 * kk + 1];
            uint4 rcv;
            rcv.x = __shfl_xor((int)snd.x, 32);
            rcv.y = __shfl_xor((int)snd.y, 32);
            rcv.z = __shfl_xor((int)snd.z, 32);
            rcv.w = __shfl_xor((int)snd.w, 32);
            uint4 fr = (q == 1 || q == 2) ? rcv : own;
            bf16x8 pa = __builtin_bit_cast(bf16x8, fr);
#pragma unroll
            for (int t = 0; t < 5; ++t) {
                bf16x8 bv = *(const bf16x8*)&Vs[(t * 16 + l15) * 104 + kk * 32 + q * 8];
                o[t] = mfma16(pa, bv, o[t]);
            }
        }
    }

    // ---- fuse + store (lane holds col d = 16t + l15, rows s = 4q + i)
    const size_t obase = ((size_t)b * 4096 + s0 + wv * 16 + q * 4) * 640 + h * 80;
#pragma unroll
    for (int t = 0; t < 5; ++t)
#pragma unroll
        for (int i = 0; i < 4; ++i)
            fused[obase + (size_t)i * 640 + t * 16 + l15] = f2bf(w0 * o0[t][i] + w1 * o1[t][i]);
}

// ---------------- launcher ----------------

extern "C" void kernel_launch(void* const* d_in, const int* in_sizes, int n_in,
                              void* d_out, int out_size, void* d_ws, size_t ws_size,
                              hipStream_t stream) {
    const float* hidden = (const float*)d_in[0];
    const float* enc    = (const float*)d_in[1];
    const float* qual   = (const float*)d_in[2];
    const float* Wq     = (const float*)d_in[3];
    const float* Wks    = (const float*)d_in[4];
    const float* Wvs    = (const float*)d_in[5];
    const float* Wkq    = (const float*)d_in[6];
    const float* Wvq    = (const float*)d_in[7];
    const float* Wout   = (const float*)d_in[8];
    const float* fw     = (const float*)d_in[9];
    float* out = (float*)d_out;

    char* ws = (char*)d_ws;
    unsigned short* hid_bf  = (unsigned short*)(ws + 0);          // 83,886,080 B (reused as `fused`)
    unsigned short* Qb      = (unsigned short*)(ws + 83886080);   // 83,886,080 B
    unsigned short* encp    = (unsigned short*)(ws + 167772160);  // [2][1280][1280]  6,553,600 B
    unsigned short* wq_bt   = (unsigned short*)(ws + 174325760);  // 819,200 B
    unsigned short* wout_bt = (unsigned short*)(ws + 175144960);  // 819,200 B
    unsigned short* wkv_bt  = (unsigned short*)(ws + 175964160);  // [2][1280][1280]  6,553,600 B
    unsigned short* kvout   = (unsigned short*)(ws + 182517760);  // [2][1280][1280]  6,553,600 B
    // Kg2 overlays encp (dead after KV GEMM); Vt2 overlays wkv_bt (dead after KV GEMM)
    unsigned short* Kg2     = encp;    // [2][16][8][80][104] = 4,259,840 B (fits 6.55 MB)
    unsigned short* Vt2     = wkv_bt;  // [2][16][8][80][104] = 4,259,840 B

    k_cvt_hidden<<<dim3(2048), dim3(256), 0, stream>>>(hidden, hid_bf, 41943040L);
    k_prep_enc<<<dim3(1024), dim3(256), 0, stream>>>(enc, qual, encp);
    k_prep_w<<<dim3(1024), dim3(256), 0, stream>>>(Wq, Wout, Wks, Wvs, Wkq, Wvq, wq_bt, wout_bt, wkv_bt);
    gemm_bt<0><<<dim3(10, 10, 2), dim3(256), 0, stream>>>(encp, wkv_bt, (void*)kvout, 1280, 1280,
                                                          1280L * 1280, 1280L * 1280, 1280L * 1280);
    k_scatter<<<dim3(1024), dim3(256), 0, stream>>>(kvout, Kg2, Vt2);
    gemm_bt<0><<<dim3(512, 5, 1), dim3(256), 0, stream>>>(hid_bf, wq_bt, (void*)Qb, 640, 640, 0L, 0L, 0L);
    attn_kernel<<<dim3(32, 8, 16), dim3(512), 0, stream>>>(Qb, Kg2, Vt2, fw, hid_bf);
    gemm_bt<1><<<dim3(512, 5, 1), dim3(256), 0, stream>>>(hid_bf, wout_bt, (void*)out, 640, 640, 0L, 0L, 0L);
}